// Round 3
// 333.061 us; speedup vs baseline: 1.0834x; 1.0834x over previous
//
#include <hip/hip_runtime.h>
#include <math.h>

// ---------------- problem constants ----------------
#define NT 512      // N_TARGET
#define NF 1024     // N_FEAT
#define NFUNC 32
#define BATCHSZ 16

// clang ext vector types — required for __builtin_nontemporal_* (HIP_vector_type is rejected)
typedef float v4f __attribute__((ext_vector_type(4)));
typedef int   v4i __attribute__((ext_vector_type(4)));

// output layout (float elements, concatenated in return order)
constexpr int O_MEM  = 0;          // 16384*512
constexpr int O_TMEM = 8388608;    // 16384 (written as float)
constexpr int O_FEAT = 8404992;    // 16384*1024
constexpr int O_ARE  = 25182208;   // 32*512
constexpr int O_AIM  = 25198592;
constexpr int O_FREQ = 25214976;   // 32
constexpr int O_RP   = 25215008;   // 1536*512
constexpr int O_BIAS = 26001440;   // 512
constexpr int O_FM   = 26001952;   // 1024
constexpr int O_AGR  = 26002976;   // 32*512
constexpr int O_AGI  = 26019360;
constexpr int O_FGR  = 26035744;   // 32
constexpr int O_RPG  = 26035776;   // 1536*512

// ws layout (floats)
constexpr int W_LR    = 0;
constexpr int W_ANORM = 2;   // [2] per-batch
constexpr int W_RNORM = 4;   // [2]
constexpr int W_GFR   = 8;   // [2*32]
constexpr int W_TB    = 72;  // [16]
constexpr int W_C     = 96;    // [16*32]
constexpr int W_S     = 608;   // [16*32]
constexpr int W_CATZ  = 1120;  // [16*512]
constexpr int W_CATX  = 9312;  // [16*1024]
constexpr int W_GR    = 25696; // [16*512]
constexpr int W_G     = 33888; // [16*512]
constexpr int W_AGRE  = 42080; // [32*512]
constexpr int W_AGIM  = 58464; // [32*512]
constexpr int W_RPART = 74848; // [16*8192] split-K partials

constexpr float MM_LR = 0.03f;
constexpr float AMP_DECAY = 0.01f;
constexpr float MOM = 0.85f;
constexpr float INV_SQRT_NF = 0.17677669529663687f; // 1/sqrt(32)
constexpr float TWO_PI = 6.283185307179586f;

constexpr int NCOPY = 256;               // copy-helper blocks per kernel
constexpr long long U_TOTAL = 6295552LL; // float4 units: mem 2097152 + feat 4194304 + tmem 4096

// float4-unit region boundaries
constexpr int R_MEM_END  = 2097152;   // memory  [0, 2097152)
constexpr int R_FEAT_END = 6291456;   // feat    [2097152, 6291456)
constexpr int R_TM_END   = 6295552;   // tmem    [6291456, 6295552)

__device__ __forceinline__ float sgnf(float x) {
    return (x > 0.f) ? 1.f : ((x < 0.f) ? -1.f : 0.f);
}

__device__ __forceinline__ float wave_reduce(float v) {
#pragma unroll
    for (int o = 32; o > 0; o >>= 1) v += __shfl_down(v, o, 64);
    return v; // lane 0 holds sum
}

// ------------- background copy: slice [cbase, cbase+ccnt) of U_TOTAL -------------
// Unit-stride per lane, region-split (branch-free address math per region),
// 4-deep load batching, nontemporal so the 201 MB stream does not evict L2
// working set (rp / ws) used by the compute blocks.
__device__ __forceinline__ void copy_role(int rb, int cbase, int ccnt,
    const int* __restrict__ tptr, const int* __restrict__ dsptr,
    const float* __restrict__ x, const float* __restrict__ z,
    const float* __restrict__ memory, const int* __restrict__ t_memory,
    const float* __restrict__ feat_memory, float* __restrict__ out)
{
    const int dsv  = *dsptr;
    const int nthr = NCOPY * 256;
    const int tg   = rb * 256 + (int)threadIdx.x;
    const int cend = cbase + ccnt;

    // ---- region 1: memory rows (row ds <- z), float4 units [0, R_MEM_END) ----
    {
        const int a1 = cend < R_MEM_END ? cend : R_MEM_END;
        const v4f* __restrict__ src = (const v4f*)memory;
        const v4f* __restrict__ zz  = (const v4f*)z;
        v4f* __restrict__ dst = (v4f*)(out + O_MEM);
        int u = cbase + tg;
        for (; u + 3 * nthr < a1; u += 4 * nthr) {
            const int u1 = u + nthr, u2 = u + 2 * nthr, u3 = u + 3 * nthr;
            v4f v0 = __builtin_nontemporal_load((u  >> 7) == dsv ? zz + (u  & 127) : src + u );
            v4f v1 = __builtin_nontemporal_load((u1 >> 7) == dsv ? zz + (u1 & 127) : src + u1);
            v4f v2 = __builtin_nontemporal_load((u2 >> 7) == dsv ? zz + (u2 & 127) : src + u2);
            v4f v3 = __builtin_nontemporal_load((u3 >> 7) == dsv ? zz + (u3 & 127) : src + u3);
            __builtin_nontemporal_store(v0, dst + u );
            __builtin_nontemporal_store(v1, dst + u1);
            __builtin_nontemporal_store(v2, dst + u2);
            __builtin_nontemporal_store(v3, dst + u3);
        }
        for (; u < a1; u += nthr) {
            v4f v = __builtin_nontemporal_load((u >> 7) == dsv ? zz + (u & 127) : src + u);
            __builtin_nontemporal_store(v, dst + u);
        }
    }
    // ---- region 2: feat rows (row ds <- x), float4 units [R_MEM_END, R_FEAT_END) ----
    {
        const int a0 = cbase > R_MEM_END ? cbase : R_MEM_END;
        const int a1 = cend < R_FEAT_END ? cend : R_FEAT_END;
        const v4f* __restrict__ src = (const v4f*)feat_memory;
        const v4f* __restrict__ xx  = (const v4f*)x;
        v4f* __restrict__ dst = (v4f*)(out + O_FEAT);
        int u = a0 + tg;
        for (; u + 3 * nthr < a1; u += 4 * nthr) {
            const int u1 = u + nthr, u2 = u + 2 * nthr, u3 = u + 3 * nthr;
            const int f0 = u - R_MEM_END, f1 = u1 - R_MEM_END,
                      f2 = u2 - R_MEM_END, f3 = u3 - R_MEM_END;
            v4f v0 = __builtin_nontemporal_load((f0 >> 8) == dsv ? xx + (f0 & 255) : src + f0);
            v4f v1 = __builtin_nontemporal_load((f1 >> 8) == dsv ? xx + (f1 & 255) : src + f1);
            v4f v2 = __builtin_nontemporal_load((f2 >> 8) == dsv ? xx + (f2 & 255) : src + f2);
            v4f v3 = __builtin_nontemporal_load((f3 >> 8) == dsv ? xx + (f3 & 255) : src + f3);
            __builtin_nontemporal_store(v0, dst + f0);
            __builtin_nontemporal_store(v1, dst + f1);
            __builtin_nontemporal_store(v2, dst + f2);
            __builtin_nontemporal_store(v3, dst + f3);
        }
        for (; u < a1; u += nthr) {
            const int f = u - R_MEM_END;
            v4f v = __builtin_nontemporal_load((f >> 8) == dsv ? xx + (f & 255) : src + f);
            __builtin_nontemporal_store(v, dst + f);
        }
    }
    // ---- region 3: t_memory -> float (elem ds <- t), float4 units [R_FEAT_END, R_TM_END) ----
    {
        const int a0 = cbase > R_FEAT_END ? cbase : R_FEAT_END;
        const int a1 = cend;
        if (a1 > a0) {
            const float ft = (float)(*tptr);
            const v4i* __restrict__ tm = (const v4i*)t_memory;
            v4f* __restrict__ dst = (v4f*)(out + O_TMEM);
            for (int u = a0 + tg; u < a1; u += nthr) {
                const int f = u - R_FEAT_END;
                const v4i iv = __builtin_nontemporal_load(tm + f);
                const int e = f * 4;
                v4f v;
                v.x = (e + 0 == dsv) ? ft : (float)iv.x;
                v.y = (e + 1 == dsv) ? ft : (float)iv.y;
                v.z = (e + 2 == dsv) ? ft : (float)iv.z;
                v.w = (e + 3 == dsv) ? ft : (float)iv.w;
                __builtin_nontemporal_store(v, dst + f);
            }
        }
    }
}

#define COPY_ARGS const int* __restrict__ tptr, const int* __restrict__ dsptr,            \
                  const float* __restrict__ x, const float* __restrict__ z,               \
                  const float* __restrict__ memory, const int* __restrict__ t_memory,     \
                  const float* __restrict__ feat_memory, int cbase, int ccnt
#define COPY_PASS tptr, dsptr, x, z, memory, t_memory, feat_memory

// ======== K1: fused cat + split-K matmul partials. block=(i, s-chunk) ========
__global__ __launch_bounds__(256) void k_fwd_ab(int b, const int* __restrict__ ts,
    const float* __restrict__ cf,
    const float* __restrict__ are_src, const float* __restrict__ aim_src,
    const float* __restrict__ fq_src, const float* __restrict__ fm_in,
    const float* __restrict__ rp_src,
    float* __restrict__ out, float* __restrict__ ws, COPY_ARGS)
{
    int bb = blockIdx.x;
    const int tid = threadIdx.x;
    if (bb < NCOPY) { copy_role(bb, cbase, ccnt, COPY_PASS, out); return; }
    bb -= NCOPY;
    const int i = bb >> 4, s = bb & 15;
    __shared__ float c_l[32], s_l[32], cat[96];
    const int dsv = *dsptr;
    const int bi = ts[b * BATCHSZ + i];
    if (tid < 32) {
        float f  = fq_src[tid];
        float th = tanhf(f);
        float u  = cf[tid] + 2.f * th;
        float sg = 1.f / (1.f + expf(-u));
        float fr = 0.5f * sg;
        float tb = (bi == dsv) ? (float)(*tptr) : (float)t_memory[bi];
        float ph = TWO_PI * tb * fr;
        float cv = cosf(ph), sv = sinf(ph);
        c_l[tid] = cv; s_l[tid] = sv;
        if (s == 0) {
            ws[W_C + i*32 + tid] = cv; ws[W_S + i*32 + tid] = sv;
            if (tid == 0) ws[W_TB + i] = tb;
        }
    }
    if (bb == 0) {  // per-batch accumulator init
        if (tid == 64) ws[W_ANORM + b] = 0.f;
        if (tid == 65) ws[W_RNORM + b] = 0.f;
        if (tid == 66 && b == 0) ws[W_LR] = (float)pow(0.977, (double)(dsv + 1));
        if (tid >= 96 && tid < 128) ws[W_GFR + b*32 + tid - 96] = 0.f;
    }
    __syncthreads();
    if (tid < 96) {                     // compute this block's 96-elem cat slice
        int p = s * 96 + tid;
        float cv;
        if (p < NF) {
            const float nn = (float)(dsv + 1), dd = (float)(dsv + 2);
            float fmv = (fm_in[p] * nn + x[p]) / dd;
            float xv  = (bi == dsv) ? x[p] : feat_memory[bi*NF + p];
            cv = xv - fmv;
            ws[W_CATX + i*NF + p] = cv;
        } else {
            int q = p - NF;
            float acc = 0.f;
#pragma unroll
            for (int k = 0; k < 32; ++k)
                acc += c_l[k] * are_src[k*NT + q] - s_l[k] * aim_src[k*NT + q];
            cv = acc * INV_SQRT_NF;     // z_ - bias
            ws[W_CATZ + i*NT + q] = cv;
        }
        cat[tid] = cv;
    }
    __syncthreads();
    const int j = tid;
    const float* rpb = rp_src + (size_t)s * 96 * NT;
    float a0 = 0.f, a1 = 0.f, b0 = 0.f, b1 = 0.f;
#pragma unroll 8
    for (int p = 0; p < 96; p += 2) {
        float c0 = cat[p], c1 = cat[p + 1];
        a0 += c0 * rpb[p*NT + j];
        a1 += c0 * rpb[p*NT + j + 256];
        b0 += c1 * rpb[(p+1)*NT + j];
        b1 += c1 * rpb[(p+1)*NT + j + 256];
    }
    ws[W_RPART + s*8192 + i*NT + j]       = a0 + b0;
    ws[W_RPART + s*8192 + i*NT + j + 256] = a1 + b1;
}

// ======== K2: epilogue — g_r + FULL G, parallel. block=(i, j-group of 8) ========
__global__ __launch_bounds__(256) void k_eplg3(int b, const int* __restrict__ ts,
    const float* __restrict__ bias_in, const float* __restrict__ fm_in,
    const float* __restrict__ rp_src,
    float* __restrict__ out, float* __restrict__ ws, COPY_ARGS)
{
    int bb = blockIdx.x;
    const int tid = threadIdx.x;
    if (bb < NCOPY) { copy_role(bb, cbase, ccnt, COPY_PASS, out); return; }
    bb -= NCOPY;
    const int i = bb >> 6, jg = bb & 63;
    __shared__ float g_sh[NT], d_sh[NT];
    const int dsv = *dsptr;
    const int bi = ts[b * BATCHSZ + i];
    const float nn = (float)(dsv + 1), dd = (float)(dsv + 2);
#pragma unroll
    for (int ll = 0; ll < 2; ++ll) {
        int l = tid + ll * 256;
        float r = 0.f;
#pragma unroll
        for (int s = 0; s < 16; ++s) r += ws[W_RPART + s*8192 + i*NT + l];
        float bn = (bias_in[l] * nn + z[l]) / dd;
        float zj = ws[W_CATZ + i*NT + l] + bn;
        float zb = (bi == dsv) ? z[l] : memory[bi*NT + l];
        float s1 = sgnf(zj - zb);
        float ar = fabsf(r) + 1.f;
        float z2 = zj + r / ar;
        float g  = sgnf(z2 - zb) * (MM_LR / 16.f) / (ar * ar);
        g_sh[l] = g; d_sh[l] = s1 * (1.f / 16.f);
        if (jg == 0) {
            ws[W_GR + i*NT + l] = g;
            if (b == 0 && i == 0) out[O_BIAS + l] = bn;
        }
    }
    if (b == 0 && jg == 0 && i < 2) {   // fm_new (i=0,1 cover 1024)
#pragma unroll
        for (int ll = 0; ll < 2; ++ll) {
            int p = i * 512 + tid + ll * 256;
            out[O_FM + p] = (fm_in[p] * nn + x[p]) / dd;
        }
    }
    __syncthreads();
    const int w = tid >> 6, lane = tid & 63;
#pragma unroll
    for (int jj = 0; jj < 2; ++jj) {
        int j = jg * 8 + w * 2 + jj;
        const float* rrow = rp_src + (size_t)(NF + j) * NT;
        float acc = 0.f;
#pragma unroll
        for (int l = lane; l < NT; l += 64) acc += g_sh[l] * rrow[l];
        acc = wave_reduce(acc);
        if (lane == 0) ws[W_G + i*NT + j] = d_sh[j] + acc;
    }
}

// ======== K3: all norms — amp grads+anorm [0,64) | gfr [64,192) | rg+rnorm [192,3264) ========
__global__ __launch_bounds__(256) void k_norms(int b,
    const float* __restrict__ are_src, const float* __restrict__ aim_src,
    float* __restrict__ out, float* __restrict__ ws, COPY_ARGS)
{
    __shared__ float red[4];
    int bb = blockIdx.x;
    const int tid = threadIdx.x;
    if (bb < NCOPY) { copy_role(bb, cbase, ccnt, COPY_PASS, out); return; }
    bb -= NCOPY;
    if (bb < 64) {
        int e = bb*256 + tid;
        int k = e >> 9;
        float gre = 0.f, gim = 0.f;
#pragma unroll
        for (int i2 = 0; i2 < 16; ++i2) {
            float G = ws[W_G + i2*NT + (e & 511)];
            gre += G * ws[W_C + i2*32 + k];
            gim += G * ws[W_S + i2*32 + k];
        }
        float re = are_src[e], im = aim_src[e];
        float aa = sqrtf(re*re + im*im);
        float dec = AMP_DECAY / (2.f * aa * sqrtf(aa));
        float agr =  gre * INV_SQRT_NF + re * dec;
        float agi = -gim * INV_SQRT_NF + im * dec;
        ws[W_AGRE + e] = agr;
        ws[W_AGIM + e] = agi;
        float v = wave_reduce(agr*agr + agi*agi);
        if ((tid & 63) == 0) red[tid >> 6] = v;
        __syncthreads();
        if (tid == 0) atomicAdd(&ws[W_ANORM + b], red[0]+red[1]+red[2]+red[3]);
    } else if (bb < 192) {
        int wid = tid >> 6, lane = tid & 63;
        int pair = (bb - 64)*4 + wid;      // 512 = 16 i x 32 k
        int i = pair >> 5, k = pair & 31;
        float ck = ws[W_C + i*32 + k], sk = ws[W_S + i*32 + k];
        float acc = 0.f;
#pragma unroll
        for (int j = lane; j < NT; j += 64)
            acc += ws[W_G + i*NT + j] * (-sk * are_src[k*NT + j] - ck * aim_src[k*NT + j]);
        acc = wave_reduce(acc);
        if (lane == 0)
            atomicAdd(&ws[W_GFR + b*32 + k], acc * TWO_PI * ws[W_TB + i] * INV_SQRT_NF);
    } else {
        int e = (bb - 192)*256 + tid;
        int p = e >> 9, j = e & 511;
        float rg = 0.f;
#pragma unroll
        for (int i2 = 0; i2 < 16; ++i2) {
            float cat = (p < NF) ? ws[W_CATX + i2*NF + p]
                                 : ws[W_CATZ + i2*NT + (p - NF)];
            rg += cat * ws[W_GR + i2*NT + j];
        }
        float v = wave_reduce(rg * rg);
        if ((tid & 63) == 0) red[tid >> 6] = v;
        __syncthreads();
        if (tid == 0) atomicAdd(&ws[W_RNORM + b], red[0]+red[1]+red[2]+red[3]);
    }
}

// ======== K4: parameter updates ========
__global__ __launch_bounds__(256) void k_upd(int b, const float* __restrict__ cf,
    const float* __restrict__ are_src, const float* __restrict__ aim_src,
    const float* __restrict__ agr_src, const float* __restrict__ agi_src,
    const float* __restrict__ fq_src,  const float* __restrict__ fgr_src,
    const float* __restrict__ rp_src,  const float* __restrict__ rpg_src,
    float* __restrict__ out, float* __restrict__ ws, COPY_ARGS)
{
    int bb = blockIdx.x;
    const int tid = threadIdx.x;
    if (bb < NCOPY) { copy_role(bb, cbase, ccnt, COPY_PASS, out); return; }
    bb -= NCOPY;
    const float lr = ws[W_LR];
    if (bb < 64) {
        int e = bb*256 + tid;
        float anorm = sqrtf(ws[W_ANORM + b]) + 1.f;
        float mr = agr_src[e]*MOM + ws[W_AGRE + e]/anorm;
        out[O_AGR + e] = mr; out[O_ARE + e] = are_src[e] - mr*lr;
        float mi = agi_src[e]*MOM + ws[W_AGIM + e]/anorm;
        out[O_AGI + e] = mi; out[O_AIM + e] = aim_src[e] - mi*lr;
    } else if (bb == 64) {
        if (tid < 64) {
            float fg = 0.f, th = 0.f;
            if (tid < 32) {
                float f = fq_src[tid];
                th = tanhf(f);
                float u  = cf[tid] + 2.f*th;
                float sg = 1.f / (1.f + expf(-u));
                fg = ws[W_GFR + b*32 + tid] * sg*(1.f-sg)*(1.f-th*th);
            }
            float t2 = fg*fg;
#pragma unroll
            for (int o = 32; o > 0; o >>= 1) t2 += __shfl_down(t2, o, 64);
            float tot = __shfl(t2, 0, 64);
            if (tid < 32) {
                float fnorm = sqrtf(tot) + 1.f;
                float m = fgr_src[tid]*MOM + fg/fnorm;
                out[O_FGR + tid] = m;
                out[O_FREQ + tid] = fq_src[tid] - m*lr;
            }
        }
    } else {
        int e = (bb - 65)*256 + tid;
        int p = e >> 9, j = e & 511;
        float rg = 0.f;
#pragma unroll
        for (int i2 = 0; i2 < 16; ++i2) {
            float cat = (p < NF) ? ws[W_CATX + i2*NF + p]
                                 : ws[W_CATZ + i2*NT + (p - NF)];
            rg += cat * ws[W_GR + i2*NT + j];   // same order as k_norms -> identical fp
        }
        float rnorm = sqrtf(ws[W_RNORM + b]) + 1.f;
        float m = rpg_src[e]*MOM + rg/rnorm;
        out[O_RPG + e] = m; out[O_RP + e] = rp_src[e] - m*lr;
    }
}

extern "C" void kernel_launch(void* const* d_in, const int* in_sizes, int n_in,
                              void* d_out, int out_size, void* d_ws, size_t ws_size,
                              hipStream_t stream)
{
    const int*   t            = (const int*)d_in[0];
    const int*   dsp          = (const int*)d_in[1];
    const int*   ts           = (const int*)d_in[2];
    const float* x            = (const float*)d_in[3];
    const float* z            = (const float*)d_in[4];
    const float* memory       = (const float*)d_in[5];
    const int*   t_memory     = (const int*)d_in[6];
    const float* feat_memory  = (const float*)d_in[7];
    const float* amp_re       = (const float*)d_in[8];
    const float* amp_im       = (const float*)d_in[9];
    const float* freq         = (const float*)d_in[10];
    const float* cf           = (const float*)d_in[11];
    const float* res_proj     = (const float*)d_in[12];
    const float* feat_mean    = (const float*)d_in[13];
    const float* bias         = (const float*)d_in[14];
    const float* amp_grad_re  = (const float*)d_in[15];
    const float* amp_grad_im  = (const float*)d_in[16];
    const float* freq_grad    = (const float*)d_in[17];
    const float* res_proj_grad= (const float*)d_in[18];
    float* out = (float*)d_out;
    float* ws  = (float*)d_ws;

    const float* ARE[2] = { amp_re,        out + O_ARE };
    const float* AIM[2] = { amp_im,        out + O_AIM };
    const float* AGR[2] = { amp_grad_re,   out + O_AGR };
    const float* AGI[2] = { amp_grad_im,   out + O_AGI };
    const float* FQ [2] = { freq,          out + O_FREQ };
    const float* FGR[2] = { freq_grad,     out + O_FGR };
    const float* RP [2] = { res_proj,      out + O_RP };
    const float* RPG[2] = { res_proj_grad, out + O_RPG };

    // 8 equal copy slices (U_TOTAL = 8 * 786944)
    const int per = 786944;
    int base = 0;
    auto nxt = [&](int& cb, int& cc) { cb = base; cc = per; base += cc; };
    int cb, cc;
    for (int b = 0; b < 2; ++b) {
        nxt(cb, cc);
        k_fwd_ab<<<256 + NCOPY, 256, 0, stream>>>(b, ts, cf, ARE[b], AIM[b], FQ[b],
            feat_mean, RP[b], out, ws, t, dsp, x, z, memory, t_memory, feat_memory, cb, cc);
        nxt(cb, cc);
        k_eplg3<<<1024 + NCOPY, 256, 0, stream>>>(b, ts, bias, feat_mean, RP[b], out, ws,
            t, dsp, x, z, memory, t_memory, feat_memory, cb, cc);
        nxt(cb, cc);
        k_norms<<<3264 + NCOPY, 256, 0, stream>>>(b, ARE[b], AIM[b], out, ws,
            t, dsp, x, z, memory, t_memory, feat_memory, cb, cc);
        nxt(cb, cc);
        k_upd<<<3137 + NCOPY, 256, 0, stream>>>(b, cf, ARE[b], AIM[b], AGR[b], AGI[b],
            FQ[b], FGR[b], RP[b], RPG[b], out, ws,
            t, dsp, x, z, memory, t_memory, feat_memory, cb, cc);
    }
}

// Round 5
// 329.273 us; speedup vs baseline: 1.0959x; 1.0115x over previous
//
#include <hip/hip_runtime.h>
#include <hip/hip_cooperative_groups.h>
#include <math.h>

namespace cg = cooperative_groups;

// ---------------- problem constants ----------------
#define NT 512      // N_TARGET
#define NF 1024     // N_FEAT
#define NFUNC 32
#define BATCHSZ 16

// clang ext vector types — required for __builtin_nontemporal_* (HIP_vector_type is rejected)
typedef float v4f __attribute__((ext_vector_type(4)));
typedef int   v4i __attribute__((ext_vector_type(4)));

// output layout (float elements, concatenated in return order)
constexpr int O_MEM  = 0;          // 16384*512
constexpr int O_TMEM = 8388608;    // 16384 (written as float)
constexpr int O_FEAT = 8404992;    // 16384*1024
constexpr int O_ARE  = 25182208;   // 32*512
constexpr int O_AIM  = 25198592;
constexpr int O_FREQ = 25214976;   // 32
constexpr int O_RP   = 25215008;   // 1536*512
constexpr int O_BIAS = 26001440;   // 512
constexpr int O_FM   = 26001952;   // 1024
constexpr int O_AGR  = 26002976;   // 32*512
constexpr int O_AGI  = 26019360;
constexpr int O_FGR  = 26035744;   // 32
constexpr int O_RPG  = 26035776;   // 1536*512

// ws layout (floats)
constexpr int W_LR    = 0;
constexpr int W_ANORM = 2;   // [2] per-batch
constexpr int W_RNORM = 4;   // [2]
constexpr int W_GFR   = 8;   // [2*32]
constexpr int W_TB    = 72;  // [16]
constexpr int W_C     = 96;    // [16*32]
constexpr int W_S     = 608;   // [16*32]
constexpr int W_CATZ  = 1120;  // [16*512]
constexpr int W_CATX  = 9312;  // [16*1024]
constexpr int W_GR    = 25696; // [16*512]
constexpr int W_G     = 33888; // [16*512]
constexpr int W_AGRE  = 42080; // [32*512]
constexpr int W_AGIM  = 58464; // [32*512]
constexpr int W_RPART = 74848; // [16*8192] split-K partials

constexpr float MM_LR = 0.03f;
constexpr float AMP_DECAY = 0.01f;
constexpr float MOM = 0.85f;
constexpr float INV_SQRT_NF = 0.17677669529663687f; // 1/sqrt(32)
constexpr float TWO_PI = 6.283185307179586f;

constexpr int NB = 512;                  // cooperative grid (2 blocks/CU on 256 CUs)
constexpr int CHUNK = 786944;            // U_TOTAL/8 float4 units per stage
constexpr int NCOPY = 256;               // fallback copy-helper blocks per kernel

// float4-unit region boundaries
constexpr int R_MEM_END  = 2097152;   // memory  [0, 2097152)
constexpr int R_FEAT_END = 6291456;   // feat    [2097152, 6291456)

struct KParams {
    const int *t, *dsp, *ts;
    const float *x, *z, *memory;
    const int *t_memory;
    const float *feat_memory;
    const float *amp_re, *amp_im, *freq, *cf, *res_proj, *feat_mean, *bias;
    const float *amp_grad_re, *amp_grad_im, *freq_grad, *res_proj_grad;
    float *out, *ws;
};

__device__ __forceinline__ float sgnf(float x) {
    return (x > 0.f) ? 1.f : ((x < 0.f) ? -1.f : 0.f);
}

__device__ __forceinline__ float wave_reduce(float v) {
#pragma unroll
    for (int o = 32; o > 0; o >>= 1) v += __shfl_down(v, o, 64);
    return v; // lane 0 holds sum
}

// ------------- generic copy: units [cbase, cend) with nthr threads, thread id tg -------------
__device__ __forceinline__ void copy_span(int tg, int nthr, int cbase, int cend,
    int dsv, int tt,
    const float* __restrict__ x, const float* __restrict__ z,
    const float* __restrict__ memory, const int* __restrict__ t_memory,
    const float* __restrict__ feat_memory, float* __restrict__ out)
{
    // ---- region 1: memory rows (row ds <- z), units [0, R_MEM_END) ----
    {
        const int a1 = cend < R_MEM_END ? cend : R_MEM_END;
        const v4f* __restrict__ src = (const v4f*)memory;
        const v4f* __restrict__ zz  = (const v4f*)z;
        v4f* __restrict__ dst = (v4f*)(out + O_MEM);
        int u = cbase + tg;
        for (; u + nthr < a1; u += 2 * nthr) {
            const int u1 = u + nthr;
            v4f v0 = __builtin_nontemporal_load((u  >> 7) == dsv ? zz + (u  & 127) : src + u );
            v4f v1 = __builtin_nontemporal_load((u1 >> 7) == dsv ? zz + (u1 & 127) : src + u1);
            __builtin_nontemporal_store(v0, dst + u );
            __builtin_nontemporal_store(v1, dst + u1);
        }
        for (; u < a1; u += nthr) {
            v4f v = __builtin_nontemporal_load((u >> 7) == dsv ? zz + (u & 127) : src + u);
            __builtin_nontemporal_store(v, dst + u);
        }
    }
    // ---- region 2: feat rows (row ds <- x), units [R_MEM_END, R_FEAT_END) ----
    {
        const int a0 = cbase > R_MEM_END ? cbase : R_MEM_END;
        const int a1 = cend < R_FEAT_END ? cend : R_FEAT_END;
        const v4f* __restrict__ src = (const v4f*)feat_memory;
        const v4f* __restrict__ xx  = (const v4f*)x;
        v4f* __restrict__ dst = (v4f*)(out + O_FEAT);
        int u = a0 + tg;
        for (; u + nthr < a1; u += 2 * nthr) {
            const int u1 = u + nthr;
            const int f0 = u - R_MEM_END, f1 = u1 - R_MEM_END;
            v4f v0 = __builtin_nontemporal_load((f0 >> 8) == dsv ? xx + (f0 & 255) : src + f0);
            v4f v1 = __builtin_nontemporal_load((f1 >> 8) == dsv ? xx + (f1 & 255) : src + f1);
            __builtin_nontemporal_store(v0, dst + f0);
            __builtin_nontemporal_store(v1, dst + f1);
        }
        for (; u < a1; u += nthr) {
            const int f = u - R_MEM_END;
            v4f v = __builtin_nontemporal_load((f >> 8) == dsv ? xx + (f & 255) : src + f);
            __builtin_nontemporal_store(v, dst + f);
        }
    }
    // ---- region 3: t_memory -> float (elem ds <- t), units [R_FEAT_END, U_TOTAL) ----
    {
        const int a0 = cbase > R_FEAT_END ? cbase : R_FEAT_END;
        const int a1 = cend;
        if (a1 > a0) {
            const float ft = (float)tt;
            const v4i* __restrict__ tm = (const v4i*)t_memory;
            v4f* __restrict__ dst = (v4f*)(out + O_TMEM);
            for (int u = a0 + tg; u < a1; u += nthr) {
                const int f = u - R_FEAT_END;
                const v4i iv = __builtin_nontemporal_load(tm + f);
                const int e = f * 4;
                v4f v;
                v.x = (e + 0 == dsv) ? ft : (float)iv.x;
                v.y = (e + 1 == dsv) ? ft : (float)iv.y;
                v.z = (e + 2 == dsv) ? ft : (float)iv.z;
                v.w = (e + 3 == dsv) ? ft : (float)iv.w;
                __builtin_nontemporal_store(v, dst + f);
            }
        }
    }
}

// ================== single fused cooperative kernel ==================
__global__ __launch_bounds__(256, 2) void k_fused(KParams p)
{
    cg::grid_group grid = cg::this_grid();
    const int bidx = (int)blockIdx.x;
    const int tid  = (int)threadIdx.x;

    __shared__ float c_l[32], s_l[32], cat[96];
    __shared__ float g_sh[NT], d_sh[NT];
    __shared__ float red[4];

    float* __restrict__ out = p.out;
    float* __restrict__ ws  = p.ws;
    const int dsv = *p.dsp;
    const int tt  = *p.t;
    const float nn = (float)(dsv + 1), dd = (float)(dsv + 2);
    const int tg   = bidx * 256 + tid;
    const int nthr = NB * 256;

    for (int b = 0; b < 2; ++b) {
        const float* __restrict__ are_src = b ? out + O_ARE : p.amp_re;
        const float* __restrict__ aim_src = b ? out + O_AIM : p.amp_im;
        const float* __restrict__ fq_src  = b ? out + O_FREQ: p.freq;
        const float* __restrict__ rp_src  = b ? out + O_RP  : p.res_proj;
        const float* __restrict__ agr_src = b ? out + O_AGR : p.amp_grad_re;
        const float* __restrict__ agi_src = b ? out + O_AGI : p.amp_grad_im;
        const float* __restrict__ fgr_src = b ? out + O_FGR : p.freq_grad;
        const float* __restrict__ rpg_src = b ? out + O_RPG : p.res_proj_grad;

        // ======== Stage A (K1): cat + split-K matmul partials (256 items, NB>=256) ========
        if (bidx < 256) {
            const int i = bidx >> 4, s = bidx & 15;
            const int bi = p.ts[b * BATCHSZ + i];
            if (tid < 32) {
                float f  = fq_src[tid];
                float th = tanhf(f);
                float u  = p.cf[tid] + 2.f * th;
                float sg = 1.f / (1.f + expf(-u));
                float fr = 0.5f * sg;
                float tb = (bi == dsv) ? (float)tt : (float)p.t_memory[bi];
                float ph = TWO_PI * tb * fr;
                float cv = cosf(ph), sv = sinf(ph);
                c_l[tid] = cv; s_l[tid] = sv;
                if (s == 0) {
                    ws[W_C + i*32 + tid] = cv; ws[W_S + i*32 + tid] = sv;
                    if (tid == 0) ws[W_TB + i] = tb;
                }
            }
            if (bidx == 0) {  // per-batch accumulator init
                if (tid == 64) ws[W_ANORM + b] = 0.f;
                if (tid == 65) ws[W_RNORM + b] = 0.f;
                if (tid == 66 && b == 0) ws[W_LR] = (float)pow(0.977, (double)(dsv + 1));
                if (tid >= 96 && tid < 128) ws[W_GFR + b*32 + tid - 96] = 0.f;
            }
            __syncthreads();
            if (tid < 96) {                     // this block's 96-elem cat slice
                int pe = s * 96 + tid;
                float cv;
                if (pe < NF) {
                    float fmv = (p.feat_mean[pe] * nn + p.x[pe]) / dd;
                    float xv  = (bi == dsv) ? p.x[pe] : p.feat_memory[bi*NF + pe];
                    cv = xv - fmv;
                    ws[W_CATX + i*NF + pe] = cv;
                } else {
                    int q = pe - NF;
                    float acc = 0.f;
#pragma unroll
                    for (int k = 0; k < 32; ++k)
                        acc += c_l[k] * are_src[k*NT + q] - s_l[k] * aim_src[k*NT + q];
                    cv = acc * INV_SQRT_NF;     // z_ - bias
                    ws[W_CATZ + i*NT + q] = cv;
                }
                cat[tid] = cv;
            }
            __syncthreads();
            const int j = tid;
            const float* rpb = rp_src + (size_t)s * 96 * NT;
            float a0 = 0.f, a1 = 0.f, b0 = 0.f, b1 = 0.f;
#pragma unroll 8
            for (int pp = 0; pp < 96; pp += 2) {
                float c0 = cat[pp], c1 = cat[pp + 1];
                a0 += c0 * rpb[pp*NT + j];
                a1 += c0 * rpb[pp*NT + j + 256];
                b0 += c1 * rpb[(pp+1)*NT + j];
                b1 += c1 * rpb[(pp+1)*NT + j + 256];
            }
            ws[W_RPART + s*8192 + i*NT + j]       = a0 + b0;
            ws[W_RPART + s*8192 + i*NT + j + 256] = a1 + b1;
        }
        {
            int cb = (b*4 + 0) * CHUNK;
            copy_span(tg, nthr, cb, cb + CHUNK, dsv, tt, p.x, p.z, p.memory, p.t_memory, p.feat_memory, out);
        }
        __threadfence();
        grid.sync();
        __threadfence();

        // ======== Stage B (K2): epilogue — g_r + full G (1024 virtual blocks) ========
        for (int vb = bidx; vb < 1024; vb += NB) {
            const int i = vb >> 6, jg = vb & 63;
            const int bi = p.ts[b * BATCHSZ + i];
#pragma unroll
            for (int ll = 0; ll < 2; ++ll) {
                int l = tid + ll * 256;
                float r = 0.f;
#pragma unroll
                for (int s = 0; s < 16; ++s) r += ws[W_RPART + s*8192 + i*NT + l];
                float bn = (p.bias[l] * nn + p.z[l]) / dd;
                float zj = ws[W_CATZ + i*NT + l] + bn;
                float zb = (bi == dsv) ? p.z[l] : p.memory[bi*NT + l];
                float s1 = sgnf(zj - zb);
                float ar = fabsf(r) + 1.f;
                float z2 = zj + r / ar;
                float g  = sgnf(z2 - zb) * (MM_LR / 16.f) / (ar * ar);
                g_sh[l] = g; d_sh[l] = s1 * (1.f / 16.f);
                if (jg == 0) {
                    ws[W_GR + i*NT + l] = g;
                    if (b == 0 && i == 0) out[O_BIAS + l] = bn;
                }
            }
            if (b == 0 && jg == 0 && i < 2) {   // fm_new (i=0,1 cover 1024)
#pragma unroll
                for (int ll = 0; ll < 2; ++ll) {
                    int pe = i * 512 + tid + ll * 256;
                    out[O_FM + pe] = (p.feat_mean[pe] * nn + p.x[pe]) / dd;
                }
            }
            __syncthreads();
            const int w = tid >> 6, lane = tid & 63;
#pragma unroll
            for (int jj = 0; jj < 2; ++jj) {
                int j = jg * 8 + w * 2 + jj;
                const float* rrow = rp_src + (size_t)(NF + j) * NT;
                float acc = 0.f;
#pragma unroll
                for (int l = lane; l < NT; l += 64) acc += g_sh[l] * rrow[l];
                acc = wave_reduce(acc);
                if (lane == 0) ws[W_G + i*NT + j] = d_sh[j] + acc;
            }
            __syncthreads();   // g_sh/d_sh reuse across virtual blocks
        }
        {
            int cb = (b*4 + 1) * CHUNK;
            copy_span(tg, nthr, cb, cb + CHUNK, dsv, tt, p.x, p.z, p.memory, p.t_memory, p.feat_memory, out);
        }
        __threadfence();
        grid.sync();
        __threadfence();

        // ======== Stage C (K3): norms ========
        for (int it = bidx; it < 3264; it += NB) {
            if (it < 64) {
                int e = it*256 + tid;
                int k = e >> 9;
                float gre = 0.f, gim = 0.f;
#pragma unroll
                for (int i2 = 0; i2 < 16; ++i2) {
                    float G = ws[W_G + i2*NT + (e & 511)];
                    gre += G * ws[W_C + i2*32 + k];
                    gim += G * ws[W_S + i2*32 + k];
                }
                float re = are_src[e], im = aim_src[e];
                float aa = sqrtf(re*re + im*im);
                float dec = AMP_DECAY / (2.f * aa * sqrtf(aa));
                float agr =  gre * INV_SQRT_NF + re * dec;
                float agi = -gim * INV_SQRT_NF + im * dec;
                ws[W_AGRE + e] = agr;
                ws[W_AGIM + e] = agi;
                float v = wave_reduce(agr*agr + agi*agi);
                if ((tid & 63) == 0) red[tid >> 6] = v;
                __syncthreads();
                if (tid == 0) atomicAdd(&ws[W_ANORM + b], red[0]+red[1]+red[2]+red[3]);
            } else if (it < 192) {
                int wid = tid >> 6, lane = tid & 63;
                int pair = (it - 64)*4 + wid;      // 512 = 16 i x 32 k
                int i = pair >> 5, k = pair & 31;
                float ck = ws[W_C + i*32 + k], sk = ws[W_S + i*32 + k];
                float acc = 0.f;
#pragma unroll
                for (int j = lane; j < NT; j += 64)
                    acc += ws[W_G + i*NT + j] * (-sk * are_src[k*NT + j] - ck * aim_src[k*NT + j]);
                acc = wave_reduce(acc);
                if (lane == 0)
                    atomicAdd(&ws[W_GFR + b*32 + k], acc * TWO_PI * ws[W_TB + i] * INV_SQRT_NF);
            } else {
                int e = (it - 192)*256 + tid;
                int pr = e >> 9, j = e & 511;
                float rg = 0.f;
#pragma unroll
                for (int i2 = 0; i2 < 16; ++i2) {
                    float cv = (pr < NF) ? ws[W_CATX + i2*NF + pr]
                                         : ws[W_CATZ + i2*NT + (pr - NF)];
                    rg += cv * ws[W_GR + i2*NT + j];
                }
                float v = wave_reduce(rg * rg);
                if ((tid & 63) == 0) red[tid >> 6] = v;
                __syncthreads();
                if (tid == 0) atomicAdd(&ws[W_RNORM + b], red[0]+red[1]+red[2]+red[3]);
            }
            __syncthreads();   // red[] reuse across items
        }
        {
            int cb = (b*4 + 2) * CHUNK;
            copy_span(tg, nthr, cb, cb + CHUNK, dsv, tt, p.x, p.z, p.memory, p.t_memory, p.feat_memory, out);
        }
        __threadfence();
        grid.sync();
        __threadfence();

        // ======== Stage D (K4): parameter updates ========
        const float lr = ws[W_LR];
        for (int it = bidx; it < 3137; it += NB) {
            if (it < 64) {
                int e = it*256 + tid;
                float anorm = sqrtf(ws[W_ANORM + b]) + 1.f;
                float mr = agr_src[e]*MOM + ws[W_AGRE + e]/anorm;
                out[O_AGR + e] = mr; out[O_ARE + e] = are_src[e] - mr*lr;
                float mi = agi_src[e]*MOM + ws[W_AGIM + e]/anorm;
                out[O_AGI + e] = mi; out[O_AIM + e] = aim_src[e] - mi*lr;
            } else if (it == 64) {
                if (tid < 64) {
                    float fg = 0.f, th = 0.f;
                    if (tid < 32) {
                        float f = fq_src[tid];
                        th = tanhf(f);
                        float u  = p.cf[tid] + 2.f*th;
                        float sg = 1.f / (1.f + expf(-u));
                        fg = ws[W_GFR + b*32 + tid] * sg*(1.f-sg)*(1.f-th*th);
                    }
                    float t2 = fg*fg;
#pragma unroll
                    for (int o = 32; o > 0; o >>= 1) t2 += __shfl_down(t2, o, 64);
                    float tot = __shfl(t2, 0, 64);
                    if (tid < 32) {
                        float fnorm = sqrtf(tot) + 1.f;
                        float m = fgr_src[tid]*MOM + fg/fnorm;
                        out[O_FGR + tid] = m;
                        out[O_FREQ + tid] = fq_src[tid] - m*lr;
                    }
                }
            } else {
                int e = (it - 65)*256 + tid;
                int pr = e >> 9, j = e & 511;
                float rg = 0.f;
#pragma unroll
                for (int i2 = 0; i2 < 16; ++i2) {
                    float cv = (pr < NF) ? ws[W_CATX + i2*NF + pr]
                                         : ws[W_CATZ + i2*NT + (pr - NF)];
                    rg += cv * ws[W_GR + i2*NT + j];   // same order as stage C -> identical fp
                }
                float rnorm = sqrtf(ws[W_RNORM + b]) + 1.f;
                float m = rpg_src[e]*MOM + rg/rnorm;
                out[O_RPG + e] = m; out[O_RP + e] = rp_src[e] - m*lr;
            }
        }
        {
            int cb = (b*4 + 3) * CHUNK;
            copy_span(tg, nthr, cb, cb + CHUNK, dsv, tt, p.x, p.z, p.memory, p.t_memory, p.feat_memory, out);
        }
        if (b == 0) { __threadfence(); grid.sync(); __threadfence(); }
    }
}

// ===================== fallback path: verified 8-kernel pipeline (round 3) =====================
__device__ __forceinline__ void copy_role(int rb, int cbase, int ccnt,
    const int* __restrict__ tptr, const int* __restrict__ dsptr,
    const float* __restrict__ x, const float* __restrict__ z,
    const float* __restrict__ memory, const int* __restrict__ t_memory,
    const float* __restrict__ feat_memory, float* __restrict__ out)
{
    const int dsv = *dsptr;
    const int tt  = *tptr;
    copy_span(rb * 256 + (int)threadIdx.x, NCOPY * 256, cbase, cbase + ccnt,
              dsv, tt, x, z, memory, t_memory, feat_memory, out);
}

#define COPY_ARGS const int* __restrict__ tptr, const int* __restrict__ dsptr,            \
                  const float* __restrict__ x, const float* __restrict__ z,               \
                  const float* __restrict__ memory, const int* __restrict__ t_memory,     \
                  const float* __restrict__ feat_memory, int cbase, int ccnt
#define COPY_PASS tptr, dsptr, x, z, memory, t_memory, feat_memory

__global__ __launch_bounds__(256) void k_fwd_ab(int b, const int* __restrict__ ts,
    const float* __restrict__ cf,
    const float* __restrict__ are_src, const float* __restrict__ aim_src,
    const float* __restrict__ fq_src, const float* __restrict__ fm_in,
    const float* __restrict__ rp_src,
    float* __restrict__ out, float* __restrict__ ws, COPY_ARGS)
{
    int bb = blockIdx.x;
    const int tid = threadIdx.x;
    if (bb < NCOPY) { copy_role(bb, cbase, ccnt, COPY_PASS, out); return; }
    bb -= NCOPY;
    const int i = bb >> 4, s = bb & 15;
    __shared__ float c_l[32], s_l[32], cat[96];
    const int dsv = *dsptr;
    const int bi = ts[b * BATCHSZ + i];
    if (tid < 32) {
        float f  = fq_src[tid];
        float th = tanhf(f);
        float u  = cf[tid] + 2.f * th;
        float sg = 1.f / (1.f + expf(-u));
        float fr = 0.5f * sg;
        float tb = (bi == dsv) ? (float)(*tptr) : (float)t_memory[bi];
        float ph = TWO_PI * tb * fr;
        float cv = cosf(ph), sv = sinf(ph);
        c_l[tid] = cv; s_l[tid] = sv;
        if (s == 0) {
            ws[W_C + i*32 + tid] = cv; ws[W_S + i*32 + tid] = sv;
            if (tid == 0) ws[W_TB + i] = tb;
        }
    }
    if (bb == 0) {
        if (tid == 64) ws[W_ANORM + b] = 0.f;
        if (tid == 65) ws[W_RNORM + b] = 0.f;
        if (tid == 66 && b == 0) ws[W_LR] = (float)pow(0.977, (double)(dsv + 1));
        if (tid >= 96 && tid < 128) ws[W_GFR + b*32 + tid - 96] = 0.f;
    }
    __syncthreads();
    if (tid < 96) {
        int p = s * 96 + tid;
        float cv;
        if (p < NF) {
            const float nn = (float)(dsv + 1), dd = (float)(dsv + 2);
            float fmv = (fm_in[p] * nn + x[p]) / dd;
            float xv  = (bi == dsv) ? x[p] : feat_memory[bi*NF + p];
            cv = xv - fmv;
            ws[W_CATX + i*NF + p] = cv;
        } else {
            int q = p - NF;
            float acc = 0.f;
#pragma unroll
            for (int k = 0; k < 32; ++k)
                acc += c_l[k] * are_src[k*NT + q] - s_l[k] * aim_src[k*NT + q];
            cv = acc * INV_SQRT_NF;
            ws[W_CATZ + i*NT + q] = cv;
        }
        cat[tid] = cv;
    }
    __syncthreads();
    const int j = tid;
    const float* rpb = rp_src + (size_t)s * 96 * NT;
    float a0 = 0.f, a1 = 0.f, b0 = 0.f, b1 = 0.f;
#pragma unroll 8
    for (int p = 0; p < 96; p += 2) {
        float c0 = cat[p], c1 = cat[p + 1];
        a0 += c0 * rpb[p*NT + j];
        a1 += c0 * rpb[p*NT + j + 256];
        b0 += c1 * rpb[(p+1)*NT + j];
        b1 += c1 * rpb[(p+1)*NT + j + 256];
    }
    ws[W_RPART + s*8192 + i*NT + j]       = a0 + b0;
    ws[W_RPART + s*8192 + i*NT + j + 256] = a1 + b1;
}

__global__ __launch_bounds__(256) void k_eplg3(int b, const int* __restrict__ ts,
    const float* __restrict__ bias_in, const float* __restrict__ fm_in,
    const float* __restrict__ rp_src,
    float* __restrict__ out, float* __restrict__ ws, COPY_ARGS)
{
    int bb = blockIdx.x;
    const int tid = threadIdx.x;
    if (bb < NCOPY) { copy_role(bb, cbase, ccnt, COPY_PASS, out); return; }
    bb -= NCOPY;
    const int i = bb >> 6, jg = bb & 63;
    __shared__ float g_sh[NT], d_sh[NT];
    const int dsv = *dsptr;
    const int bi = ts[b * BATCHSZ + i];
    const float nn = (float)(dsv + 1), dd = (float)(dsv + 2);
#pragma unroll
    for (int ll = 0; ll < 2; ++ll) {
        int l = tid + ll * 256;
        float r = 0.f;
#pragma unroll
        for (int s = 0; s < 16; ++s) r += ws[W_RPART + s*8192 + i*NT + l];
        float bn = (bias_in[l] * nn + z[l]) / dd;
        float zj = ws[W_CATZ + i*NT + l] + bn;
        float zb = (bi == dsv) ? z[l] : memory[bi*NT + l];
        float s1 = sgnf(zj - zb);
        float ar = fabsf(r) + 1.f;
        float z2 = zj + r / ar;
        float g  = sgnf(z2 - zb) * (MM_LR / 16.f) / (ar * ar);
        g_sh[l] = g; d_sh[l] = s1 * (1.f / 16.f);
        if (jg == 0) {
            ws[W_GR + i*NT + l] = g;
            if (b == 0 && i == 0) out[O_BIAS + l] = bn;
        }
    }
    if (b == 0 && jg == 0 && i < 2) {
#pragma unroll
        for (int ll = 0; ll < 2; ++ll) {
            int p = i * 512 + tid + ll * 256;
            out[O_FM + p] = (fm_in[p] * nn + x[p]) / dd;
        }
    }
    __syncthreads();
    const int w = tid >> 6, lane = tid & 63;
#pragma unroll
    for (int jj = 0; jj < 2; ++jj) {
        int j = jg * 8 + w * 2 + jj;
        const float* rrow = rp_src + (size_t)(NF + j) * NT;
        float acc = 0.f;
#pragma unroll
        for (int l = lane; l < NT; l += 64) acc += g_sh[l] * rrow[l];
        acc = wave_reduce(acc);
        if (lane == 0) ws[W_G + i*NT + j] = d_sh[j] + acc;
    }
}

__global__ __launch_bounds__(256) void k_norms(int b,
    const float* __restrict__ are_src, const float* __restrict__ aim_src,
    float* __restrict__ out, float* __restrict__ ws, COPY_ARGS)
{
    __shared__ float red[4];
    int bb = blockIdx.x;
    const int tid = threadIdx.x;
    if (bb < NCOPY) { copy_role(bb, cbase, ccnt, COPY_PASS, out); return; }
    bb -= NCOPY;
    if (bb < 64) {
        int e = bb*256 + tid;
        int k = e >> 9;
        float gre = 0.f, gim = 0.f;
#pragma unroll
        for (int i2 = 0; i2 < 16; ++i2) {
            float G = ws[W_G + i2*NT + (e & 511)];
            gre += G * ws[W_C + i2*32 + k];
            gim += G * ws[W_S + i2*32 + k];
        }
        float re = are_src[e], im = aim_src[e];
        float aa = sqrtf(re*re + im*im);
        float dec = AMP_DECAY / (2.f * aa * sqrtf(aa));
        float agr =  gre * INV_SQRT_NF + re * dec;
        float agi = -gim * INV_SQRT_NF + im * dec;
        ws[W_AGRE + e] = agr;
        ws[W_AGIM + e] = agi;
        float v = wave_reduce(agr*agr + agi*agi);
        if ((tid & 63) == 0) red[tid >> 6] = v;
        __syncthreads();
        if (tid == 0) atomicAdd(&ws[W_ANORM + b], red[0]+red[1]+red[2]+red[3]);
    } else if (bb < 192) {
        int wid = tid >> 6, lane = tid & 63;
        int pair = (bb - 64)*4 + wid;
        int i = pair >> 5, k = pair & 31;
        float ck = ws[W_C + i*32 + k], sk = ws[W_S + i*32 + k];
        float acc = 0.f;
#pragma unroll
        for (int j = lane; j < NT; j += 64)
            acc += ws[W_G + i*NT + j] * (-sk * are_src[k*NT + j] - ck * aim_src[k*NT + j]);
        acc = wave_reduce(acc);
        if (lane == 0)
            atomicAdd(&ws[W_GFR + b*32 + k], acc * TWO_PI * ws[W_TB + i] * INV_SQRT_NF);
    } else {
        int e = (bb - 192)*256 + tid;
        int p = e >> 9, j = e & 511;
        float rg = 0.f;
#pragma unroll
        for (int i2 = 0; i2 < 16; ++i2) {
            float cat = (p < NF) ? ws[W_CATX + i2*NF + p]
                                 : ws[W_CATZ + i2*NT + (p - NF)];
            rg += cat * ws[W_GR + i2*NT + j];
        }
        float v = wave_reduce(rg * rg);
        if ((tid & 63) == 0) red[tid >> 6] = v;
        __syncthreads();
        if (tid == 0) atomicAdd(&ws[W_RNORM + b], red[0]+red[1]+red[2]+red[3]);
    }
}

__global__ __launch_bounds__(256) void k_upd(int b, const float* __restrict__ cf,
    const float* __restrict__ are_src, const float* __restrict__ aim_src,
    const float* __restrict__ agr_src, const float* __restrict__ agi_src,
    const float* __restrict__ fq_src,  const float* __restrict__ fgr_src,
    const float* __restrict__ rp_src,  const float* __restrict__ rpg_src,
    float* __restrict__ out, float* __restrict__ ws, COPY_ARGS)
{
    int bb = blockIdx.x;
    const int tid = threadIdx.x;
    if (bb < NCOPY) { copy_role(bb, cbase, ccnt, COPY_PASS, out); return; }
    bb -= NCOPY;
    const float lr = ws[W_LR];
    if (bb < 64) {
        int e = bb*256 + tid;
        float anorm = sqrtf(ws[W_ANORM + b]) + 1.f;
        float mr = agr_src[e]*MOM + ws[W_AGRE + e]/anorm;
        out[O_AGR + e] = mr; out[O_ARE + e] = are_src[e] - mr*lr;
        float mi = agi_src[e]*MOM + ws[W_AGIM + e]/anorm;
        out[O_AGI + e] = mi; out[O_AIM + e] = aim_src[e] - mi*lr;
    } else if (bb == 64) {
        if (tid < 64) {
            float fg = 0.f, th = 0.f;
            if (tid < 32) {
                float f = fq_src[tid];
                th = tanhf(f);
                float u  = cf[tid] + 2.f*th;
                float sg = 1.f / (1.f + expf(-u));
                fg = ws[W_GFR + b*32 + tid] * sg*(1.f-sg)*(1.f-th*th);
            }
            float t2 = fg*fg;
#pragma unroll
            for (int o = 32; o > 0; o >>= 1) t2 += __shfl_down(t2, o, 64);
            float tot = __shfl(t2, 0, 64);
            if (tid < 32) {
                float fnorm = sqrtf(tot) + 1.f;
                float m = fgr_src[tid]*MOM + fg/fnorm;
                out[O_FGR + tid] = m;
                out[O_FREQ + tid] = fq_src[tid] - m*lr;
            }
        }
    } else {
        int e = (bb - 65)*256 + tid;
        int p = e >> 9, j = e & 511;
        float rg = 0.f;
#pragma unroll
        for (int i2 = 0; i2 < 16; ++i2) {
            float cat = (p < NF) ? ws[W_CATX + i2*NF + p]
                                 : ws[W_CATZ + i2*NT + (p - NF)];
            rg += cat * ws[W_GR + i2*NT + j];
        }
        float rnorm = sqrtf(ws[W_RNORM + b]) + 1.f;
        float m = rpg_src[e]*MOM + rg/rnorm;
        out[O_RPG + e] = m; out[O_RP + e] = rp_src[e] - m*lr;
    }
}

extern "C" void kernel_launch(void* const* d_in, const int* in_sizes, int n_in,
                              void* d_out, int out_size, void* d_ws, size_t ws_size,
                              hipStream_t stream)
{
    const int*   t            = (const int*)d_in[0];
    const int*   dsp          = (const int*)d_in[1];
    const int*   ts           = (const int*)d_in[2];
    const float* x            = (const float*)d_in[3];
    const float* z            = (const float*)d_in[4];
    const float* memory       = (const float*)d_in[5];
    const int*   t_memory     = (const int*)d_in[6];
    const float* feat_memory  = (const float*)d_in[7];
    const float* amp_re       = (const float*)d_in[8];
    const float* amp_im       = (const float*)d_in[9];
    const float* freq         = (const float*)d_in[10];
    const float* cf           = (const float*)d_in[11];
    const float* res_proj     = (const float*)d_in[12];
    const float* feat_mean    = (const float*)d_in[13];
    const float* bias         = (const float*)d_in[14];
    const float* amp_grad_re  = (const float*)d_in[15];
    const float* amp_grad_im  = (const float*)d_in[16];
    const float* freq_grad    = (const float*)d_in[17];
    const float* res_proj_grad= (const float*)d_in[18];
    float* out = (float*)d_out;
    float* ws  = (float*)d_ws;

    // ---- decide cooperative viability once (host-only queries, capture-safe) ----
    static int coop_ok = -1;
    if (coop_ok < 0) {
        int dev = 0;
        hipGetDevice(&dev);
        hipDeviceProp_t prop;
        int ok = (hipGetDeviceProperties(&prop, dev) == hipSuccess);
        int maxb = 0;
        if (ok) ok = (hipOccupancyMaxActiveBlocksPerMultiprocessor(&maxb, k_fused, 256, 0) == hipSuccess);
        coop_ok = (ok && prop.cooperativeLaunch &&
                   (long long)maxb * prop.multiProcessorCount >= NB) ? 1 : 0;
    }

    if (coop_ok == 1) {
        KParams p;
        p.t = t; p.dsp = dsp; p.ts = ts; p.x = x; p.z = z; p.memory = memory;
        p.t_memory = t_memory; p.feat_memory = feat_memory;
        p.amp_re = amp_re; p.amp_im = amp_im; p.freq = freq; p.cf = cf;
        p.res_proj = res_proj; p.feat_mean = feat_mean; p.bias = bias;
        p.amp_grad_re = amp_grad_re; p.amp_grad_im = amp_grad_im;
        p.freq_grad = freq_grad; p.res_proj_grad = res_proj_grad;
        p.out = out; p.ws = ws;
        void* args[] = { (void*)&p };
        hipError_t e = hipLaunchCooperativeKernel(reinterpret_cast<void*>(k_fused),
                                                  dim3(NB), dim3(256), args, 0, stream);
        if (e == hipSuccess) return;
        coop_ok = 0;   // fall through to verified multi-kernel path
    }

    const float* ARE[2] = { amp_re,        out + O_ARE };
    const float* AIM[2] = { amp_im,        out + O_AIM };
    const float* AGR[2] = { amp_grad_re,   out + O_AGR };
    const float* AGI[2] = { amp_grad_im,   out + O_AGI };
    const float* FQ [2] = { freq,          out + O_FREQ };
    const float* FGR[2] = { freq_grad,     out + O_FGR };
    const float* RP [2] = { res_proj,      out + O_RP };
    const float* RPG[2] = { res_proj_grad, out + O_RPG };

    const int per = 786944;
    int base = 0;
    auto nxt = [&](int& cb, int& cc) { cb = base; cc = per; base += cc; };
    int cb, cc;
    for (int b = 0; b < 2; ++b) {
        nxt(cb, cc);
        k_fwd_ab<<<256 + NCOPY, 256, 0, stream>>>(b, ts, cf, ARE[b], AIM[b], FQ[b],
            feat_mean, RP[b], out, ws, t, dsp, x, z, memory, t_memory, feat_memory, cb, cc);
        nxt(cb, cc);
        k_eplg3<<<1024 + NCOPY, 256, 0, stream>>>(b, ts, bias, feat_mean, RP[b], out, ws,
            t, dsp, x, z, memory, t_memory, feat_memory, cb, cc);
        nxt(cb, cc);
        k_norms<<<3264 + NCOPY, 256, 0, stream>>>(b, ARE[b], AIM[b], out, ws,
            t, dsp, x, z, memory, t_memory, feat_memory, cb, cc);
        nxt(cb, cc);
        k_upd<<<3137 + NCOPY, 256, 0, stream>>>(b, cf, ARE[b], AIM[b], AGR[b], AGI[b],
            FQ[b], FGR[b], RP[b], RPG[b], out, ws,
            t, dsp, x, z, memory, t_memory, feat_memory, cb, cc);
    }
}

// Round 6
// 328.578 us; speedup vs baseline: 1.0982x; 1.0021x over previous
//
#include <hip/hip_runtime.h>
#include <math.h>

// ---------------- problem constants ----------------
#define NT 512      // N_TARGET
#define NF 1024     // N_FEAT
#define NFUNC 32
#define BATCHSZ 16

// clang ext vector types — required for __builtin_nontemporal_* (HIP_vector_type is rejected)
typedef float v4f __attribute__((ext_vector_type(4)));
typedef int   v4i __attribute__((ext_vector_type(4)));

// output layout (float elements, concatenated in return order)
constexpr int O_MEM  = 0;          // 16384*512
constexpr int O_TMEM = 8388608;    // 16384 (written as float)
constexpr int O_FEAT = 8404992;    // 16384*1024
constexpr int O_ARE  = 25182208;   // 32*512
constexpr int O_AIM  = 25198592;
constexpr int O_FREQ = 25214976;   // 32
constexpr int O_RP   = 25215008;   // 1536*512
constexpr int O_BIAS = 26001440;   // 512
constexpr int O_FM   = 26001952;   // 1024
constexpr int O_AGR  = 26002976;   // 32*512
constexpr int O_AGI  = 26019360;
constexpr int O_FGR  = 26035744;   // 32
constexpr int O_RPG  = 26035776;   // 1536*512

// ws layout (floats)
constexpr int W_LR    = 0;
constexpr int W_ANORM = 2;   // [2] per-batch
constexpr int W_RNORM = 4;   // [2]
constexpr int W_GFR   = 8;   // [2*32]
constexpr int W_TB    = 72;  // [16]
constexpr int W_BARU  = 88;  // [8] uint barrier slots (88..95 unused gap)
constexpr int W_C     = 96;    // [16*32]
constexpr int W_S     = 608;   // [16*32]
constexpr int W_CATZ  = 1120;  // [16*512]
constexpr int W_CATX  = 9312;  // [16*1024]
constexpr int W_GR    = 25696; // [16*512]
constexpr int W_G     = 33888; // [16*512]
constexpr int W_AGRE  = 42080; // [32*512]
constexpr int W_AGIM  = 58464; // [32*512]
constexpr int W_RPART = 74848; // [16*8192] split-K partials

constexpr float MM_LR = 0.03f;
constexpr float AMP_DECAY = 0.01f;
constexpr float MOM = 0.85f;
constexpr float INV_SQRT_NF = 0.17677669529663687f; // 1/sqrt(32)
constexpr float TWO_PI = 6.283185307179586f;

constexpr int NB = 1024;                 // fused grid: 4 blocks/CU on 256 CUs (guaranteed co-resident)
constexpr int CHUNK = 786944;            // U_TOTAL/8 float4 units per stage
constexpr int NCOPY = 256;               // fallback copy-helper blocks per kernel

// float4-unit region boundaries
constexpr int R_MEM_END  = 2097152;   // memory  [0, 2097152)
constexpr int R_FEAT_END = 6291456;   // feat    [2097152, 6291456)

struct KParams {
    const int *t, *dsp, *ts;
    const float *x, *z, *memory;
    const int *t_memory;
    const float *feat_memory;
    const float *amp_re, *amp_im, *freq, *cf, *res_proj, *feat_mean, *bias;
    const float *amp_grad_re, *amp_grad_im, *freq_grad, *res_proj_grad;
    float *out, *ws;
};

__device__ __forceinline__ float sgnf(float x) {
    return (x > 0.f) ? 1.f : ((x < 0.f) ? -1.f : 0.f);
}

__device__ __forceinline__ float wave_reduce(float v) {
#pragma unroll
    for (int o = 32; o > 0; o >>= 1) v += __shfl_down(v, o, 64);
    return v; // lane 0 holds sum
}

// -------- lightweight global barrier: per-slot counter (zeroed by host memset each launch) --------
// Arrive: one agent-scope RMW per block (release). Wait: ONLY thread 0 spins on acquire loads
// (L2-invalidating) with s_sleep backoff; __syncthreads broadcasts. Avoids CG's all-thread
// coherent spin that measured ~185 us/sync (round-5 rocprof: k_fused 1307 us, VALUBusy 1.4%).
__device__ __forceinline__ void gbar(unsigned* c, unsigned nb) {
    __syncthreads();
    __threadfence();
    if (threadIdx.x == 0) {
        __hip_atomic_fetch_add(c, 1u, __ATOMIC_ACQ_REL, __HIP_MEMORY_SCOPE_AGENT);
        while (__hip_atomic_load(c, __ATOMIC_ACQUIRE, __HIP_MEMORY_SCOPE_AGENT) < nb)
            __builtin_amdgcn_s_sleep(8);
    }
    __syncthreads();
}

// ------------- generic copy: units [cbase, cend) with nthr threads, thread id tg -------------
__device__ __forceinline__ void copy_span(int tg, int nthr, int cbase, int cend,
    int dsv, int tt,
    const float* __restrict__ x, const float* __restrict__ z,
    const float* __restrict__ memory, const int* __restrict__ t_memory,
    const float* __restrict__ feat_memory, float* __restrict__ out)
{
    // ---- region 1: memory rows (row ds <- z), units [0, R_MEM_END) ----
    {
        const int a1 = cend < R_MEM_END ? cend : R_MEM_END;
        const v4f* __restrict__ src = (const v4f*)memory;
        const v4f* __restrict__ zz  = (const v4f*)z;
        v4f* __restrict__ dst = (v4f*)(out + O_MEM);
        int u = cbase + tg;
        for (; u + nthr < a1; u += 2 * nthr) {
            const int u1 = u + nthr;
            v4f v0 = __builtin_nontemporal_load((u  >> 7) == dsv ? zz + (u  & 127) : src + u );
            v4f v1 = __builtin_nontemporal_load((u1 >> 7) == dsv ? zz + (u1 & 127) : src + u1);
            __builtin_nontemporal_store(v0, dst + u );
            __builtin_nontemporal_store(v1, dst + u1);
        }
        for (; u < a1; u += nthr) {
            v4f v = __builtin_nontemporal_load((u >> 7) == dsv ? zz + (u & 127) : src + u);
            __builtin_nontemporal_store(v, dst + u);
        }
    }
    // ---- region 2: feat rows (row ds <- x), units [R_MEM_END, R_FEAT_END) ----
    {
        const int a0 = cbase > R_MEM_END ? cbase : R_MEM_END;
        const int a1 = cend < R_FEAT_END ? cend : R_FEAT_END;
        const v4f* __restrict__ src = (const v4f*)feat_memory;
        const v4f* __restrict__ xx  = (const v4f*)x;
        v4f* __restrict__ dst = (v4f*)(out + O_FEAT);
        int u = a0 + tg;
        for (; u + nthr < a1; u += 2 * nthr) {
            const int u1 = u + nthr;
            const int f0 = u - R_MEM_END, f1 = u1 - R_MEM_END;
            v4f v0 = __builtin_nontemporal_load((f0 >> 8) == dsv ? xx + (f0 & 255) : src + f0);
            v4f v1 = __builtin_nontemporal_load((f1 >> 8) == dsv ? xx + (f1 & 255) : src + f1);
            __builtin_nontemporal_store(v0, dst + f0);
            __builtin_nontemporal_store(v1, dst + f1);
        }
        for (; u < a1; u += nthr) {
            const int f = u - R_MEM_END;
            v4f v = __builtin_nontemporal_load((f >> 8) == dsv ? xx + (f & 255) : src + f);
            __builtin_nontemporal_store(v, dst + f);
        }
    }
    // ---- region 3: t_memory -> float (elem ds <- t), units [R_FEAT_END, U_TOTAL) ----
    {
        const int a0 = cbase > R_FEAT_END ? cbase : R_FEAT_END;
        const int a1 = cend;
        if (a1 > a0) {
            const float ft = (float)tt;
            const v4i* __restrict__ tm = (const v4i*)t_memory;
            v4f* __restrict__ dst = (v4f*)(out + O_TMEM);
            for (int u = a0 + tg; u < a1; u += nthr) {
                const int f = u - R_FEAT_END;
                const v4i iv = __builtin_nontemporal_load(tm + f);
                const int e = f * 4;
                v4f v;
                v.x = (e + 0 == dsv) ? ft : (float)iv.x;
                v.y = (e + 1 == dsv) ? ft : (float)iv.y;
                v.z = (e + 2 == dsv) ? ft : (float)iv.z;
                v.w = (e + 3 == dsv) ? ft : (float)iv.w;
                __builtin_nontemporal_store(v, dst + f);
            }
        }
    }
}

// ================== single fused kernel (plain launch, hand-rolled barrier) ==================
__global__ __launch_bounds__(256, 4) void k_fused2(KParams p)
{
    const int bidx = (int)blockIdx.x;
    const int tid  = (int)threadIdx.x;

    __shared__ float c_l[32], s_l[32], cat[96];
    __shared__ float g_sh[NT], d_sh[NT];
    __shared__ float red[4];

    float* __restrict__ out = p.out;
    float* __restrict__ ws  = p.ws;
    unsigned* bars = (unsigned*)(ws + W_BARU);
    int bs = 0;
    const int dsv = *p.dsp;
    const int tt  = *p.t;
    const float nn = (float)(dsv + 1), dd = (float)(dsv + 2);
    const int tg   = bidx * 256 + tid;
    const int nthr = NB * 256;

    for (int b = 0; b < 2; ++b) {
        const float* __restrict__ are_src = b ? out + O_ARE : p.amp_re;
        const float* __restrict__ aim_src = b ? out + O_AIM : p.amp_im;
        const float* __restrict__ fq_src  = b ? out + O_FREQ: p.freq;
        const float* __restrict__ rp_src  = b ? out + O_RP  : p.res_proj;
        const float* __restrict__ agr_src = b ? out + O_AGR : p.amp_grad_re;
        const float* __restrict__ agi_src = b ? out + O_AGI : p.amp_grad_im;
        const float* __restrict__ fgr_src = b ? out + O_FGR : p.freq_grad;
        const float* __restrict__ rpg_src = b ? out + O_RPG : p.res_proj_grad;

        // ======== Stage A (K1): cat + split-K matmul partials (256 items) ========
        if (bidx < 256) {
            const int i = bidx >> 4, s = bidx & 15;
            const int bi = p.ts[b * BATCHSZ + i];
            if (tid < 32) {
                float f  = fq_src[tid];
                float th = tanhf(f);
                float u  = p.cf[tid] + 2.f * th;
                float sg = 1.f / (1.f + expf(-u));
                float fr = 0.5f * sg;
                float tb = (bi == dsv) ? (float)tt : (float)p.t_memory[bi];
                float ph = TWO_PI * tb * fr;
                float cv = cosf(ph), sv = sinf(ph);
                c_l[tid] = cv; s_l[tid] = sv;
                if (s == 0) {
                    ws[W_C + i*32 + tid] = cv; ws[W_S + i*32 + tid] = sv;
                    if (tid == 0) ws[W_TB + i] = tb;
                }
            }
            if (bidx == 0) {  // per-batch accumulator init
                if (tid == 64) ws[W_ANORM + b] = 0.f;
                if (tid == 65) ws[W_RNORM + b] = 0.f;
                if (tid == 66 && b == 0) ws[W_LR] = (float)pow(0.977, (double)(dsv + 1));
                if (tid >= 96 && tid < 128) ws[W_GFR + b*32 + tid - 96] = 0.f;
            }
            __syncthreads();
            if (tid < 96) {                     // this block's 96-elem cat slice
                int pe = s * 96 + tid;
                float cv;
                if (pe < NF) {
                    float fmv = (p.feat_mean[pe] * nn + p.x[pe]) / dd;
                    float xv  = (bi == dsv) ? p.x[pe] : p.feat_memory[bi*NF + pe];
                    cv = xv - fmv;
                    ws[W_CATX + i*NF + pe] = cv;
                } else {
                    int q = pe - NF;
                    float acc = 0.f;
#pragma unroll
                    for (int k = 0; k < 32; ++k)
                        acc += c_l[k] * are_src[k*NT + q] - s_l[k] * aim_src[k*NT + q];
                    cv = acc * INV_SQRT_NF;     // z_ - bias
                    ws[W_CATZ + i*NT + q] = cv;
                }
                cat[tid] = cv;
            }
            __syncthreads();
            const int j = tid;
            const float* rpb = rp_src + (size_t)s * 96 * NT;
            float a0 = 0.f, a1 = 0.f, b0 = 0.f, b1 = 0.f;
#pragma unroll 8
            for (int pp = 0; pp < 96; pp += 2) {
                float c0 = cat[pp], c1 = cat[pp + 1];
                a0 += c0 * rpb[pp*NT + j];
                a1 += c0 * rpb[pp*NT + j + 256];
                b0 += c1 * rpb[(pp+1)*NT + j];
                b1 += c1 * rpb[(pp+1)*NT + j + 256];
            }
            ws[W_RPART + s*8192 + i*NT + j]       = a0 + b0;
            ws[W_RPART + s*8192 + i*NT + j + 256] = a1 + b1;
        }
        {
            int cb = (b*4 + 0) * CHUNK;
            copy_span(tg, nthr, cb, cb + CHUNK, dsv, tt, p.x, p.z, p.memory, p.t_memory, p.feat_memory, out);
        }
        gbar(&bars[bs++], NB);

        // ======== Stage B (K2): epilogue — g_r + full G (1024 items) ========
        for (int vb = bidx; vb < 1024; vb += NB) {
            const int i = vb >> 6, jg = vb & 63;
            const int bi = p.ts[b * BATCHSZ + i];
#pragma unroll
            for (int ll = 0; ll < 2; ++ll) {
                int l = tid + ll * 256;
                float r = 0.f;
#pragma unroll
                for (int s = 0; s < 16; ++s) r += ws[W_RPART + s*8192 + i*NT + l];
                float bn = (p.bias[l] * nn + p.z[l]) / dd;
                float zj = ws[W_CATZ + i*NT + l] + bn;
                float zb = (bi == dsv) ? p.z[l] : p.memory[bi*NT + l];
                float s1 = sgnf(zj - zb);
                float ar = fabsf(r) + 1.f;
                float z2 = zj + r / ar;
                float g  = sgnf(z2 - zb) * (MM_LR / 16.f) / (ar * ar);
                g_sh[l] = g; d_sh[l] = s1 * (1.f / 16.f);
                if (jg == 0) {
                    ws[W_GR + i*NT + l] = g;
                    if (b == 0 && i == 0) out[O_BIAS + l] = bn;
                }
            }
            if (b == 0 && jg == 0 && i < 2) {   // fm_new (i=0,1 cover 1024)
#pragma unroll
                for (int ll = 0; ll < 2; ++ll) {
                    int pe = i * 512 + tid + ll * 256;
                    out[O_FM + pe] = (p.feat_mean[pe] * nn + p.x[pe]) / dd;
                }
            }
            __syncthreads();
            const int w = tid >> 6, lane = tid & 63;
#pragma unroll
            for (int jj = 0; jj < 2; ++jj) {
                int j = jg * 8 + w * 2 + jj;
                const float* rrow = rp_src + (size_t)(NF + j) * NT;
                float acc = 0.f;
#pragma unroll
                for (int l = lane; l < NT; l += 64) acc += g_sh[l] * rrow[l];
                acc = wave_reduce(acc);
                if (lane == 0) ws[W_G + i*NT + j] = d_sh[j] + acc;
            }
            __syncthreads();   // g_sh/d_sh reuse safety
        }
        {
            int cb = (b*4 + 1) * CHUNK;
            copy_span(tg, nthr, cb, cb + CHUNK, dsv, tt, p.x, p.z, p.memory, p.t_memory, p.feat_memory, out);
        }
        gbar(&bars[bs++], NB);

        // ======== Stage C (K3): norms ========
        for (int it = bidx; it < 3264; it += NB) {
            if (it < 64) {
                int e = it*256 + tid;
                int k = e >> 9;
                float gre = 0.f, gim = 0.f;
#pragma unroll
                for (int i2 = 0; i2 < 16; ++i2) {
                    float G = ws[W_G + i2*NT + (e & 511)];
                    gre += G * ws[W_C + i2*32 + k];
                    gim += G * ws[W_S + i2*32 + k];
                }
                float re = are_src[e], im = aim_src[e];
                float aa = sqrtf(re*re + im*im);
                float dec = AMP_DECAY / (2.f * aa * sqrtf(aa));
                float agr =  gre * INV_SQRT_NF + re * dec;
                float agi = -gim * INV_SQRT_NF + im * dec;
                ws[W_AGRE + e] = agr;
                ws[W_AGIM + e] = agi;
                float v = wave_reduce(agr*agr + agi*agi);
                if ((tid & 63) == 0) red[tid >> 6] = v;
                __syncthreads();
                if (tid == 0) atomicAdd(&ws[W_ANORM + b], red[0]+red[1]+red[2]+red[3]);
            } else if (it < 192) {
                int wid = tid >> 6, lane = tid & 63;
                int pair = (it - 64)*4 + wid;      // 512 = 16 i x 32 k
                int i = pair >> 5, k = pair & 31;
                float ck = ws[W_C + i*32 + k], sk = ws[W_S + i*32 + k];
                float acc = 0.f;
#pragma unroll
                for (int j = lane; j < NT; j += 64)
                    acc += ws[W_G + i*NT + j] * (-sk * are_src[k*NT + j] - ck * aim_src[k*NT + j]);
                acc = wave_reduce(acc);
                if (lane == 0)
                    atomicAdd(&ws[W_GFR + b*32 + k], acc * TWO_PI * ws[W_TB + i] * INV_SQRT_NF);
            } else {
                int e = (it - 192)*256 + tid;
                int pr = e >> 9, j = e & 511;
                float rg = 0.f;
#pragma unroll
                for (int i2 = 0; i2 < 16; ++i2) {
                    float cv = (pr < NF) ? ws[W_CATX + i2*NF + pr]
                                         : ws[W_CATZ + i2*NT + (pr - NF)];
                    rg += cv * ws[W_GR + i2*NT + j];
                }
                float v = wave_reduce(rg * rg);
                if ((tid & 63) == 0) red[tid >> 6] = v;
                __syncthreads();
                if (tid == 0) atomicAdd(&ws[W_RNORM + b], red[0]+red[1]+red[2]+red[3]);
            }
            __syncthreads();   // red[] reuse across items
        }
        {
            int cb = (b*4 + 2) * CHUNK;
            copy_span(tg, nthr, cb, cb + CHUNK, dsv, tt, p.x, p.z, p.memory, p.t_memory, p.feat_memory, out);
        }
        gbar(&bars[bs++], NB);

        // ======== Stage D (K4): parameter updates ========
        const float lr = ws[W_LR];
        for (int it = bidx; it < 3137; it += NB) {
            if (it < 64) {
                int e = it*256 + tid;
                float anorm = sqrtf(ws[W_ANORM + b]) + 1.f;
                float mr = agr_src[e]*MOM + ws[W_AGRE + e]/anorm;
                out[O_AGR + e] = mr; out[O_ARE + e] = are_src[e] - mr*lr;
                float mi = agi_src[e]*MOM + ws[W_AGIM + e]/anorm;
                out[O_AGI + e] = mi; out[O_AIM + e] = aim_src[e] - mi*lr;
            } else if (it == 64) {
                if (tid < 64) {
                    float fg = 0.f, th = 0.f;
                    if (tid < 32) {
                        float f = fq_src[tid];
                        th = tanhf(f);
                        float u  = p.cf[tid] + 2.f*th;
                        float sg = 1.f / (1.f + expf(-u));
                        fg = ws[W_GFR + b*32 + tid] * sg*(1.f-sg)*(1.f-th*th);
                    }
                    float t2 = fg*fg;
#pragma unroll
                    for (int o = 32; o > 0; o >>= 1) t2 += __shfl_down(t2, o, 64);
                    float tot = __shfl(t2, 0, 64);
                    if (tid < 32) {
                        float fnorm = sqrtf(tot) + 1.f;
                        float m = fgr_src[tid]*MOM + fg/fnorm;
                        out[O_FGR + tid] = m;
                        out[O_FREQ + tid] = fq_src[tid] - m*lr;
                    }
                }
            } else {
                int e = (it - 65)*256 + tid;
                int pr = e >> 9, j = e & 511;
                float rg = 0.f;
#pragma unroll
                for (int i2 = 0; i2 < 16; ++i2) {
                    float cv = (pr < NF) ? ws[W_CATX + i2*NF + pr]
                                         : ws[W_CATZ + i2*NT + (pr - NF)];
                    rg += cv * ws[W_GR + i2*NT + j];   // same order as stage C -> identical fp
                }
                float rnorm = sqrtf(ws[W_RNORM + b]) + 1.f;
                float m = rpg_src[e]*MOM + rg/rnorm;
                out[O_RPG + e] = m; out[O_RP + e] = rp_src[e] - m*lr;
            }
        }
        {
            int cb = (b*4 + 3) * CHUNK;
            copy_span(tg, nthr, cb, cb + CHUNK, dsv, tt, p.x, p.z, p.memory, p.t_memory, p.feat_memory, out);
        }
        if (b == 0) gbar(&bars[bs++], NB);
    }
}

// ===================== fallback path: verified 8-kernel pipeline (round 3) =====================
__device__ __forceinline__ void copy_role(int rb, int cbase, int ccnt,
    const int* __restrict__ tptr, const int* __restrict__ dsptr,
    const float* __restrict__ x, const float* __restrict__ z,
    const float* __restrict__ memory, const int* __restrict__ t_memory,
    const float* __restrict__ feat_memory, float* __restrict__ out)
{
    const int dsv = *dsptr;
    const int tt  = *tptr;
    copy_span(rb * 256 + (int)threadIdx.x, NCOPY * 256, cbase, cbase + ccnt,
              dsv, tt, x, z, memory, t_memory, feat_memory, out);
}

#define COPY_ARGS const int* __restrict__ tptr, const int* __restrict__ dsptr,            \
                  const float* __restrict__ x, const float* __restrict__ z,               \
                  const float* __restrict__ memory, const int* __restrict__ t_memory,     \
                  const float* __restrict__ feat_memory, int cbase, int ccnt
#define COPY_PASS tptr, dsptr, x, z, memory, t_memory, feat_memory

__global__ __launch_bounds__(256) void k_fwd_ab(int b, const int* __restrict__ ts,
    const float* __restrict__ cf,
    const float* __restrict__ are_src, const float* __restrict__ aim_src,
    const float* __restrict__ fq_src, const float* __restrict__ fm_in,
    const float* __restrict__ rp_src,
    float* __restrict__ out, float* __restrict__ ws, COPY_ARGS)
{
    int bb = blockIdx.x;
    const int tid = threadIdx.x;
    if (bb < NCOPY) { copy_role(bb, cbase, ccnt, COPY_PASS, out); return; }
    bb -= NCOPY;
    const int i = bb >> 4, s = bb & 15;
    __shared__ float c_l[32], s_l[32], cat[96];
    const int dsv = *dsptr;
    const int bi = ts[b * BATCHSZ + i];
    if (tid < 32) {
        float f  = fq_src[tid];
        float th = tanhf(f);
        float u  = cf[tid] + 2.f * th;
        float sg = 1.f / (1.f + expf(-u));
        float fr = 0.5f * sg;
        float tb = (bi == dsv) ? (float)(*tptr) : (float)t_memory[bi];
        float ph = TWO_PI * tb * fr;
        float cv = cosf(ph), sv = sinf(ph);
        c_l[tid] = cv; s_l[tid] = sv;
        if (s == 0) {
            ws[W_C + i*32 + tid] = cv; ws[W_S + i*32 + tid] = sv;
            if (tid == 0) ws[W_TB + i] = tb;
        }
    }
    if (bb == 0) {
        if (tid == 64) ws[W_ANORM + b] = 0.f;
        if (tid == 65) ws[W_RNORM + b] = 0.f;
        if (tid == 66 && b == 0) ws[W_LR] = (float)pow(0.977, (double)(dsv + 1));
        if (tid >= 96 && tid < 128) ws[W_GFR + b*32 + tid - 96] = 0.f;
    }
    __syncthreads();
    if (tid < 96) {
        int p = s * 96 + tid;
        float cv;
        if (p < NF) {
            const float nn = (float)(dsv + 1), dd = (float)(dsv + 2);
            float fmv = (fm_in[p] * nn + x[p]) / dd;
            float xv  = (bi == dsv) ? x[p] : feat_memory[bi*NF + p];
            cv = xv - fmv;
            ws[W_CATX + i*NF + p] = cv;
        } else {
            int q = p - NF;
            float acc = 0.f;
#pragma unroll
            for (int k = 0; k < 32; ++k)
                acc += c_l[k] * are_src[k*NT + q] - s_l[k] * aim_src[k*NT + q];
            cv = acc * INV_SQRT_NF;
            ws[W_CATZ + i*NT + q] = cv;
        }
        cat[tid] = cv;
    }
    __syncthreads();
    const int j = tid;
    const float* rpb = rp_src + (size_t)s * 96 * NT;
    float a0 = 0.f, a1 = 0.f, b0 = 0.f, b1 = 0.f;
#pragma unroll 8
    for (int p = 0; p < 96; p += 2) {
        float c0 = cat[p], c1 = cat[p + 1];
        a0 += c0 * rpb[p*NT + j];
        a1 += c0 * rpb[p*NT + j + 256];
        b0 += c1 * rpb[(p+1)*NT + j];
        b1 += c1 * rpb[(p+1)*NT + j + 256];
    }
    ws[W_RPART + s*8192 + i*NT + j]       = a0 + b0;
    ws[W_RPART + s*8192 + i*NT + j + 256] = a1 + b1;
}

__global__ __launch_bounds__(256) void k_eplg3(int b, const int* __restrict__ ts,
    const float* __restrict__ bias_in, const float* __restrict__ fm_in,
    const float* __restrict__ rp_src,
    float* __restrict__ out, float* __restrict__ ws, COPY_ARGS)
{
    int bb = blockIdx.x;
    const int tid = threadIdx.x;
    if (bb < NCOPY) { copy_role(bb, cbase, ccnt, COPY_PASS, out); return; }
    bb -= NCOPY;
    const int i = bb >> 6, jg = bb & 63;
    __shared__ float g_sh[NT], d_sh[NT];
    const int dsv = *dsptr;
    const int bi = ts[b * BATCHSZ + i];
    const float nn = (float)(dsv + 1), dd = (float)(dsv + 2);
#pragma unroll
    for (int ll = 0; ll < 2; ++ll) {
        int l = tid + ll * 256;
        float r = 0.f;
#pragma unroll
        for (int s = 0; s < 16; ++s) r += ws[W_RPART + s*8192 + i*NT + l];
        float bn = (bias_in[l] * nn + z[l]) / dd;
        float zj = ws[W_CATZ + i*NT + l] + bn;
        float zb = (bi == dsv) ? z[l] : memory[bi*NT + l];
        float s1 = sgnf(zj - zb);
        float ar = fabsf(r) + 1.f;
        float z2 = zj + r / ar;
        float g  = sgnf(z2 - zb) * (MM_LR / 16.f) / (ar * ar);
        g_sh[l] = g; d_sh[l] = s1 * (1.f / 16.f);
        if (jg == 0) {
            ws[W_GR + i*NT + l] = g;
            if (b == 0 && i == 0) out[O_BIAS + l] = bn;
        }
    }
    if (b == 0 && jg == 0 && i < 2) {
#pragma unroll
        for (int ll = 0; ll < 2; ++ll) {
            int p = i * 512 + tid + ll * 256;
            out[O_FM + p] = (fm_in[p] * nn + x[p]) / dd;
        }
    }
    __syncthreads();
    const int w = tid >> 6, lane = tid & 63;
#pragma unroll
    for (int jj = 0; jj < 2; ++jj) {
        int j = jg * 8 + w * 2 + jj;
        const float* rrow = rp_src + (size_t)(NF + j) * NT;
        float acc = 0.f;
#pragma unroll
        for (int l = lane; l < NT; l += 64) acc += g_sh[l] * rrow[l];
        acc = wave_reduce(acc);
        if (lane == 0) ws[W_G + i*NT + j] = d_sh[j] + acc;
    }
}

__global__ __launch_bounds__(256) void k_norms(int b,
    const float* __restrict__ are_src, const float* __restrict__ aim_src,
    float* __restrict__ out, float* __restrict__ ws, COPY_ARGS)
{
    __shared__ float red[4];
    int bb = blockIdx.x;
    const int tid = threadIdx.x;
    if (bb < NCOPY) { copy_role(bb, cbase, ccnt, COPY_PASS, out); return; }
    bb -= NCOPY;
    if (bb < 64) {
        int e = bb*256 + tid;
        int k = e >> 9;
        float gre = 0.f, gim = 0.f;
#pragma unroll
        for (int i2 = 0; i2 < 16; ++i2) {
            float G = ws[W_G + i2*NT + (e & 511)];
            gre += G * ws[W_C + i2*32 + k];
            gim += G * ws[W_S + i2*32 + k];
        }
        float re = are_src[e], im = aim_src[e];
        float aa = sqrtf(re*re + im*im);
        float dec = AMP_DECAY / (2.f * aa * sqrtf(aa));
        float agr =  gre * INV_SQRT_NF + re * dec;
        float agi = -gim * INV_SQRT_NF + im * dec;
        ws[W_AGRE + e] = agr;
        ws[W_AGIM + e] = agi;
        float v = wave_reduce(agr*agr + agi*agi);
        if ((tid & 63) == 0) red[tid >> 6] = v;
        __syncthreads();
        if (tid == 0) atomicAdd(&ws[W_ANORM + b], red[0]+red[1]+red[2]+red[3]);
    } else if (bb < 192) {
        int wid = tid >> 6, lane = tid & 63;
        int pair = (bb - 64)*4 + wid;
        int i = pair >> 5, k = pair & 31;
        float ck = ws[W_C + i*32 + k], sk = ws[W_S + i*32 + k];
        float acc = 0.f;
#pragma unroll
        for (int j = lane; j < NT; j += 64)
            acc += ws[W_G + i*NT + j] * (-sk * are_src[k*NT + j] - ck * aim_src[k*NT + j]);
        acc = wave_reduce(acc);
        if (lane == 0)
            atomicAdd(&ws[W_GFR + b*32 + k], acc * TWO_PI * ws[W_TB + i] * INV_SQRT_NF);
    } else {
        int e = (bb - 192)*256 + tid;
        int p = e >> 9, j = e & 511;
        float rg = 0.f;
#pragma unroll
        for (int i2 = 0; i2 < 16; ++i2) {
            float cat = (p < NF) ? ws[W_CATX + i2*NF + p]
                                 : ws[W_CATZ + i2*NT + (p - NF)];
            rg += cat * ws[W_GR + i2*NT + j];
        }
        float v = wave_reduce(rg * rg);
        if ((tid & 63) == 0) red[tid >> 6] = v;
        __syncthreads();
        if (tid == 0) atomicAdd(&ws[W_RNORM + b], red[0]+red[1]+red[2]+red[3]);
    }
}

__global__ __launch_bounds__(256) void k_upd(int b, const float* __restrict__ cf,
    const float* __restrict__ are_src, const float* __restrict__ aim_src,
    const float* __restrict__ agr_src, const float* __restrict__ agi_src,
    const float* __restrict__ fq_src,  const float* __restrict__ fgr_src,
    const float* __restrict__ rp_src,  const float* __restrict__ rpg_src,
    float* __restrict__ out, float* __restrict__ ws, COPY_ARGS)
{
    int bb = blockIdx.x;
    const int tid = threadIdx.x;
    if (bb < NCOPY) { copy_role(bb, cbase, ccnt, COPY_PASS, out); return; }
    bb -= NCOPY;
    const float lr = ws[W_LR];
    if (bb < 64) {
        int e = bb*256 + tid;
        float anorm = sqrtf(ws[W_ANORM + b]) + 1.f;
        float mr = agr_src[e]*MOM + ws[W_AGRE + e]/anorm;
        out[O_AGR + e] = mr; out[O_ARE + e] = are_src[e] - mr*lr;
        float mi = agi_src[e]*MOM + ws[W_AGIM + e]/anorm;
        out[O_AGI + e] = mi; out[O_AIM + e] = aim_src[e] - mi*lr;
    } else if (bb == 64) {
        if (tid < 64) {
            float fg = 0.f, th = 0.f;
            if (tid < 32) {
                float f = fq_src[tid];
                th = tanhf(f);
                float u  = cf[tid] + 2.f*th;
                float sg = 1.f / (1.f + expf(-u));
                fg = ws[W_GFR + b*32 + tid] * sg*(1.f-sg)*(1.f-th*th);
            }
            float t2 = fg*fg;
#pragma unroll
            for (int o = 32; o > 0; o >>= 1) t2 += __shfl_down(t2, o, 64);
            float tot = __shfl(t2, 0, 64);
            if (tid < 32) {
                float fnorm = sqrtf(tot) + 1.f;
                float m = fgr_src[tid]*MOM + fg/fnorm;
                out[O_FGR + tid] = m;
                out[O_FREQ + tid] = fq_src[tid] - m*lr;
            }
        }
    } else {
        int e = (bb - 65)*256 + tid;
        int p = e >> 9, j = e & 511;
        float rg = 0.f;
#pragma unroll
        for (int i2 = 0; i2 < 16; ++i2) {
            float cat = (p < NF) ? ws[W_CATX + i2*NF + p]
                                 : ws[W_CATZ + i2*NT + (p - NF)];
            rg += cat * ws[W_GR + i2*NT + j];
        }
        float rnorm = sqrtf(ws[W_RNORM + b]) + 1.f;
        float m = rpg_src[e]*MOM + rg/rnorm;
        out[O_RPG + e] = m; out[O_RP + e] = rp_src[e] - m*lr;
    }
}

extern "C" void kernel_launch(void* const* d_in, const int* in_sizes, int n_in,
                              void* d_out, int out_size, void* d_ws, size_t ws_size,
                              hipStream_t stream)
{
    const int*   t            = (const int*)d_in[0];
    const int*   dsp          = (const int*)d_in[1];
    const int*   ts           = (const int*)d_in[2];
    const float* x            = (const float*)d_in[3];
    const float* z            = (const float*)d_in[4];
    const float* memory       = (const float*)d_in[5];
    const int*   t_memory     = (const int*)d_in[6];
    const float* feat_memory  = (const float*)d_in[7];
    const float* amp_re       = (const float*)d_in[8];
    const float* amp_im       = (const float*)d_in[9];
    const float* freq         = (const float*)d_in[10];
    const float* cf           = (const float*)d_in[11];
    const float* res_proj     = (const float*)d_in[12];
    const float* feat_mean    = (const float*)d_in[13];
    const float* bias         = (const float*)d_in[14];
    const float* amp_grad_re  = (const float*)d_in[15];
    const float* amp_grad_im  = (const float*)d_in[16];
    const float* freq_grad    = (const float*)d_in[17];
    const float* res_proj_grad= (const float*)d_in[18];
    float* out = (float*)d_out;
    float* ws  = (float*)d_ws;

    // host-only occupancy check: fused path needs all NB blocks co-resident
    int fused_ok = 0;
    {
        int dev = 0;
        if (hipGetDevice(&dev) == hipSuccess) {
            hipDeviceProp_t prop;
            int maxb = 0;
            if (hipGetDeviceProperties(&prop, dev) == hipSuccess &&
                hipOccupancyMaxActiveBlocksPerMultiprocessor(&maxb, k_fused2, 256, 0) == hipSuccess)
                fused_ok = ((long long)maxb * prop.multiProcessorCount >= NB) ? 1 : 0;
        }
    }

    if (fused_ok) {
        // zero the 8 barrier slots (capture-legal async memset, ordered before the kernel)
        hipMemsetAsync((void*)(ws + W_BARU), 0, 8 * sizeof(unsigned), stream);
        KParams p;
        p.t = t; p.dsp = dsp; p.ts = ts; p.x = x; p.z = z; p.memory = memory;
        p.t_memory = t_memory; p.feat_memory = feat_memory;
        p.amp_re = amp_re; p.amp_im = amp_im; p.freq = freq; p.cf = cf;
        p.res_proj = res_proj; p.feat_mean = feat_mean; p.bias = bias;
        p.amp_grad_re = amp_grad_re; p.amp_grad_im = amp_grad_im;
        p.freq_grad = freq_grad; p.res_proj_grad = res_proj_grad;
        p.out = out; p.ws = ws;
        k_fused2<<<NB, 256, 0, stream>>>(p);
        return;
    }

    // verified 8-kernel fallback
    const float* ARE[2] = { amp_re,        out + O_ARE };
    const float* AIM[2] = { amp_im,        out + O_AIM };
    const float* AGR[2] = { amp_grad_re,   out + O_AGR };
    const float* AGI[2] = { amp_grad_im,   out + O_AGI };
    const float* FQ [2] = { freq,          out + O_FREQ };
    const float* FGR[2] = { freq_grad,     out + O_FGR };
    const float* RP [2] = { res_proj,      out + O_RP };
    const float* RPG[2] = { res_proj_grad, out + O_RPG };

    const int per = 786944;
    int base = 0;
    auto nxt = [&](int& cb, int& cc) { cb = base; cc = per; base += cc; };
    int cb, cc;
    for (int b = 0; b < 2; ++b) {
        nxt(cb, cc);
        k_fwd_ab<<<256 + NCOPY, 256, 0, stream>>>(b, ts, cf, ARE[b], AIM[b], FQ[b],
            feat_mean, RP[b], out, ws, t, dsp, x, z, memory, t_memory, feat_memory, cb, cc);
        nxt(cb, cc);
        k_eplg3<<<1024 + NCOPY, 256, 0, stream>>>(b, ts, bias, feat_mean, RP[b], out, ws,
            t, dsp, x, z, memory, t_memory, feat_memory, cb, cc);
        nxt(cb, cc);
        k_norms<<<3264 + NCOPY, 256, 0, stream>>>(b, ARE[b], AIM[b], out, ws,
            t, dsp, x, z, memory, t_memory, feat_memory, cb, cc);
        nxt(cb, cc);
        k_upd<<<3137 + NCOPY, 256, 0, stream>>>(b, cf, ARE[b], AIM[b], AGR[b], AGI[b],
            FQ[b], FGR[b], RP[b], RPG[b], out, ws,
            t, dsp, x, z, memory, t_memory, feat_memory, cb, cc);
    }
}